// Round 13
// baseline (1720.715 us; speedup 1.0000x reference)
//
#include <hip/hip_runtime.h>
#include <hip/hip_bf16.h>
#include <math.h>

// ---------------------------------------------------------------------------
// Dims (fixed per reference)
// ---------------------------------------------------------------------------
#define BATCH   16384
#define D_IN    1024
#define H1_DIM  512
#define H2_DIM  256
#define H3_DIM  128
#define D_CBP   2048
#define H_C     1024
#define CLASSES 10
#define SLOPE   0.2f

// FFT-domain dims: rfft bins k = 0..1024 (1025), padded to 1088 complex
// -> 2176 real columns (Re,Im interleaved), = 17 tiles of 128.
// Non-zero real columns: 2*1025 = 2050 -> K-trim to 2080 (mult of 32).
#define NK_PAD  1088
#define NF      (2 * NK_PAD)   // 2176
#define NF_USED 2080           // K-trim for G4' (cols 2050.. are zeros)

typedef short v8s __attribute__((ext_vector_type(8)));
typedef float v4f __attribute__((ext_vector_type(4)));
typedef unsigned short u16;
typedef unsigned int   u32;

__device__ __forceinline__ float b2f(unsigned short u) {
  return __uint_as_float(((unsigned)u) << 16);
}
__device__ __forceinline__ u16 f2b(float f) {
  __hip_bfloat16 h = __float2bfloat16(f);   // RNE
  return __builtin_bit_cast(unsigned short, h);
}

// twiddle (cos,sin)(2π idx/2048) — same expression the old table used,
// so values are bit-identical to the r8 tab[] path.
__device__ __forceinline__ float2 twiddle(int idx) {
  const float ang = 6.2831853071795864769f * (float)idx / 2048.f;
  return make_float2(__cosf(ang), __sinf(ang));
}

// async 16B global->LDS (direct-to-shared DMA). LDS dest = wave-uniform base
// + lane*16 -> LDS layout is forced packed lane-order.
__device__ __forceinline__ void g2l16(const void* g, void* l) {
  __builtin_amdgcn_global_load_lds(
      (const __attribute__((address_space(1))) void*)g,
      (__attribute__((address_space(3))) void*)l, 16, 0, 0);
}

// ---------------------------------------------------------------------------
// 128^2 bf16 MFMA GEMM (verified r6-r9 engine): 4 waves, BK=32, 5-buffer
// ring, prefetch depth 3, one barrier/step, counted vmcnt (12/8/4/0).
// Granule rotation swizzle at the GLOBAL address -> conflict-free ds_read.
// Bijective XCD swizzle. Used for G2/G3/FWt (small/odd-N GEMMs).
// ---------------------------------------------------------------------------
__global__ __launch_bounds__(256) void gemm_bf16(
    const u16* __restrict__ A,   // [M][lda] bf16
    const u16* __restrict__ Bt,  // [N][ldb] bf16  (weights pre-transposed)
    const float* __restrict__ bias,
    u16* __restrict__ C,         // [M][N] bf16
    int M, int N, int K, int lda, int ldb, float slope)
{
  __shared__ __align__(16) short Asb[5][128 * 32];   // 40 KiB
  __shared__ __align__(16) short Bsb[5][128 * 32];   // 40 KiB

  const int tid  = threadIdx.x;
  const int wave = tid >> 6, lane = tid & 63;
  const int wm = wave >> 1, wn = wave & 1;
  const int u = lane & 15, quad = lane >> 4;

  const int nwg = gridDim.x * gridDim.y;
  int id = blockIdx.y * gridDim.x + blockIdx.x;
  if ((nwg & 7) == 0) id = (id & 7) * (nwg >> 3) + (id >> 3);
  const int m0 = (id / gridDim.x) * 128, n0 = (id % gridDim.x) * 128;

  const int g_log = ((lane & 3) - ((lane >> 3) & 3)) & 3;
  const int srow  = wave * 32 + (lane >> 2);
  const u16* gA0 = A  + (size_t)(m0 + srow)      * lda + g_log * 8;
  const u16* gA1 = A  + (size_t)(m0 + srow + 16) * lda + g_log * 8;
  const u16* gB0 = Bt + (size_t)(n0 + srow)      * ldb + g_log * 8;
  const u16* gB1 = Bt + (size_t)(n0 + srow + 16) * ldb + g_log * 8;
  const int lo0 = (wave * 32)      * 32;
  const int lo1 = (wave * 32 + 16) * 32;

  const int gran = (quad + (u >> 1)) & 3;
  int offA[4], offB[4];
#pragma unroll
  for (int i = 0; i < 4; ++i) {
    offA[i] = (wm * 64 + i * 16 + u) * 32 + gran * 8;
    offB[i] = (wn * 64 + i * 16 + u) * 32 + gran * 8;
  }

  v4f acc[4][4];
#pragma unroll
  for (int i = 0; i < 4; ++i)
#pragma unroll
    for (int j = 0; j < 4; ++j) acc[i][j] = (v4f){0.f, 0.f, 0.f, 0.f};

  const int nsteps = K >> 5;   // BK=32

  auto stage = [&](int s, int buf) {
    const int k0 = s * 32;
    g2l16(gA0 + k0, &Asb[buf][lo0]);
    g2l16(gA1 + k0, &Asb[buf][lo1]);
    g2l16(gB0 + k0, &Bsb[buf][lo0]);
    g2l16(gB1 + k0, &Bsb[buf][lo1]);
  };

  stage(0, 0);
  if (nsteps > 1) stage(1, 1);
  if (nsteps > 2) stage(2, 2);

  int cb = 0, sb = 3;   // compute-buffer, stage-buffer (wrap mod 5)
  for (int t = 0; t < nsteps; ++t) {
    if (t + 3 < nsteps) stage(t + 3, sb);

    const int rem = nsteps - 1 - t;
    if (rem >= 3)      asm volatile("s_waitcnt vmcnt(12)" ::: "memory");
    else if (rem == 2) asm volatile("s_waitcnt vmcnt(8)"  ::: "memory");
    else if (rem == 1) asm volatile("s_waitcnt vmcnt(4)"  ::: "memory");
    else               asm volatile("s_waitcnt vmcnt(0)"  ::: "memory");
    __builtin_amdgcn_s_barrier();
    asm volatile("" ::: "memory");   // pin ds_reads below the barrier

    v8s a[4], b[4];
#pragma unroll
    for (int i = 0; i < 4; ++i) a[i] = *(const v8s*)&Asb[cb][offA[i]];
#pragma unroll
    for (int j = 0; j < 4; ++j) b[j] = *(const v8s*)&Bsb[cb][offB[j]];
    __builtin_amdgcn_s_setprio(1);
#pragma unroll
    for (int i = 0; i < 4; ++i)
#pragma unroll
      for (int j = 0; j < 4; ++j)
        acc[i][j] = __builtin_amdgcn_mfma_f32_16x16x32_bf16(a[i], b[j], acc[i][j], 0, 0, 0);
    __builtin_amdgcn_s_setprio(0);

    cb = (cb == 4) ? 0 : cb + 1;
    sb = (sb == 4) ? 0 : sb + 1;
  }

  // C/D layout (m89-verified): col = lane&15, row = quad*4 + reg
  float bcol[4];
#pragma unroll
  for (int j = 0; j < 4; ++j) bcol[j] = bias[n0 + wn * 64 + j * 16 + u];
#pragma unroll
  for (int i = 0; i < 4; ++i)
#pragma unroll
    for (int r = 0; r < 4; ++r) {
      const size_t ro = (size_t)(m0 + wm * 64 + i * 16 + quad * 4 + r) * N
                        + n0 + wn * 64 + u;
#pragma unroll
      for (int j = 0; j < 4; ++j) {
        float v = acc[i][j][r] + bcol[j];
        v = v >= 0.f ? v : slope * v;
        C[ro + j * 16] = f2b(v);
      }
    }
}

// ---------------------------------------------------------------------------
// 256^2 bf16 MFMA GEMM, r13: zero-copy register double-buffering with a
// PINNED register budget.
// r12 post-mortem: without the 2nd launch_bounds arg the allocator targets
// 4 waves/SIMD = 128 VGPR/wave; the dual register sets need ~240 -> 3.5 GB
// of scratch spill traffic (FETCH 1.15 GB, MfmaUtil 3%). A 512-thread block
// is 8 waves = 2/SIMD minimum anyway, so __launch_bounds__(512, 2) raises
// the budget to 256 unified regs (acc -> AGPR half) with NO residency loss.
// Schedule unchanged from r12: even steps compute (A0,B0) while prefetching
// (A1,B1); odd steps swap; no v_mov tail (r11's 48 movs/step). Prologue
// vmcnt(8), steady vmcnt(4), tail 0. Hazards as proven in r10-r12.
// Accumulation order identical -> bit-identical results.
// Requires M%256==0 && N%256==0 (G1, G4').
// ---------------------------------------------------------------------------
__global__ __launch_bounds__(512, 2) void gemm256_bf16(
    const u16* __restrict__ A,   // [M][lda] bf16
    const u16* __restrict__ Bt,  // [N][ldb] bf16
    const float* __restrict__ bias,
    u16* __restrict__ C,         // [M][N] bf16
    int M, int N, int K, int lda, int ldb, float slope)
{
  __shared__ __align__(16) short Asb[4][256 * 32];   // 64 KiB
  __shared__ __align__(16) short Bsb[4][256 * 32];   // 64 KiB

  const int tid  = threadIdx.x;
  const int wave = tid >> 6, lane = tid & 63;
  const int wm = wave >> 2, wn = wave & 3;     // 2 x 4 wave grid
  const int u = lane & 15, quad = lane >> 4;

  const int nwg = gridDim.x * gridDim.y;
  int id = blockIdx.y * gridDim.x + blockIdx.x;
  if ((nwg & 7) == 0) id = (id & 7) * (nwg >> 3) + (id >> 3);
  const int m0 = (id / gridDim.x) * 256, n0 = (id % gridDim.x) * 256;

  const int g_log = ((lane & 3) - ((lane >> 3) & 3)) & 3;
  const int srow  = wave * 32 + (lane >> 2);   // 8 waves -> rows 0..255
  const u16* gA0 = A  + (size_t)(m0 + srow)      * lda + g_log * 8;
  const u16* gA1 = A  + (size_t)(m0 + srow + 16) * lda + g_log * 8;
  const u16* gB0 = Bt + (size_t)(n0 + srow)      * ldb + g_log * 8;
  const u16* gB1 = Bt + (size_t)(n0 + srow + 16) * ldb + g_log * 8;
  const int lo0 = (wave * 32)      * 32;
  const int lo1 = (wave * 32 + 16) * 32;

  const int gran = (quad + (u >> 1)) & 3;
  int offA[8], offB[4];
#pragma unroll
  for (int i = 0; i < 8; ++i)
    offA[i] = (wm * 128 + i * 16 + u) * 32 + gran * 8;
#pragma unroll
  for (int j = 0; j < 4; ++j)
    offB[j] = (wn * 64 + j * 16 + u) * 32 + gran * 8;

  v4f acc[8][4];
#pragma unroll
  for (int i = 0; i < 8; ++i)
#pragma unroll
    for (int j = 0; j < 4; ++j) acc[i][j] = (v4f){0.f, 0.f, 0.f, 0.f};

  const int nsteps = K >> 5;   // BK=32

  auto stage = [&](int s) {
    const int k0 = s * 32, buf = s & 3;
    g2l16(gA0 + k0, &Asb[buf][lo0]);
    g2l16(gA1 + k0, &Asb[buf][lo1]);
    g2l16(gB0 + k0, &Bsb[buf][lo0]);
    g2l16(gB1 + k0, &Bsb[buf][lo1]);
  };

  // prologue: stage 0..2, wait step 0, pre-issue reads of buf0 into set 0
  stage(0);
  if (nsteps > 1) stage(1);
  if (nsteps > 2) stage(2);
  if (nsteps > 2)      asm volatile("s_waitcnt vmcnt(8)" ::: "memory");
  else if (nsteps > 1) asm volatile("s_waitcnt vmcnt(4)" ::: "memory");
  else                 asm volatile("s_waitcnt vmcnt(0)" ::: "memory");
  __builtin_amdgcn_s_barrier();
  asm volatile("" ::: "memory");

  v8s A0r[8], B0r[4], A1r[8], B1r[4];
#pragma unroll
  for (int i = 0; i < 8; ++i) A0r[i] = *(const v8s*)&Asb[0][offA[i]];
#pragma unroll
  for (int j = 0; j < 4; ++j) B0r[j] = *(const v8s*)&Bsb[0][offB[j]];

  int t = 0;
  while (true) {
    // ---- even phase: compute t from (A0r,B0r), prefetch t+1 -> (A1r,B1r)
    {
      const int rem = nsteps - 1 - t;
      if (rem > 0) {
        if (rem >= 2) asm volatile("s_waitcnt vmcnt(4)" ::: "memory");
        else          asm volatile("s_waitcnt vmcnt(0)" ::: "memory");
        __builtin_amdgcn_s_barrier();
        asm volatile("" ::: "memory");
        const int nb = (t + 1) & 3;
#pragma unroll
        for (int i = 0; i < 8; ++i) A1r[i] = *(const v8s*)&Asb[nb][offA[i]];
#pragma unroll
        for (int j = 0; j < 4; ++j) B1r[j] = *(const v8s*)&Bsb[nb][offB[j]];
      }
      __builtin_amdgcn_s_setprio(1);
#pragma unroll
      for (int i = 0; i < 8; ++i)
#pragma unroll
        for (int j = 0; j < 4; ++j)
          acc[i][j] = __builtin_amdgcn_mfma_f32_16x16x32_bf16(A0r[i], B0r[j], acc[i][j], 0, 0, 0);
      __builtin_amdgcn_s_setprio(0);
      if (t + 3 < nsteps) stage(t + 3);
      ++t;
      if (t >= nsteps) break;
    }
    // ---- odd phase: compute t from (A1r,B1r), prefetch t+1 -> (A0r,B0r)
    {
      const int rem = nsteps - 1 - t;
      if (rem > 0) {
        if (rem >= 2) asm volatile("s_waitcnt vmcnt(4)" ::: "memory");
        else          asm volatile("s_waitcnt vmcnt(0)" ::: "memory");
        __builtin_amdgcn_s_barrier();
        asm volatile("" ::: "memory");
        const int nb = (t + 1) & 3;
#pragma unroll
        for (int i = 0; i < 8; ++i) A0r[i] = *(const v8s*)&Asb[nb][offA[i]];
#pragma unroll
        for (int j = 0; j < 4; ++j) B0r[j] = *(const v8s*)&Bsb[nb][offB[j]];
      }
      __builtin_amdgcn_s_setprio(1);
#pragma unroll
      for (int i = 0; i < 8; ++i)
#pragma unroll
        for (int j = 0; j < 4; ++j)
          acc[i][j] = __builtin_amdgcn_mfma_f32_16x16x32_bf16(A1r[i], B1r[j], acc[i][j], 0, 0, 0);
      __builtin_amdgcn_s_setprio(0);
      if (t + 3 < nsteps) stage(t + 3);
      ++t;
      if (t >= nsteps) break;
    }
  }

  // C/D layout: col = lane&15, row = quad*4 + reg
  float bcol[4];
#pragma unroll
  for (int j = 0; j < 4; ++j) bcol[j] = bias[n0 + wn * 64 + j * 16 + u];
#pragma unroll
  for (int i = 0; i < 8; ++i)
#pragma unroll
    for (int r = 0; r < 4; ++r) {
      const size_t ro = (size_t)(m0 + wm * 128 + i * 16 + quad * 4 + r) * N
                        + n0 + wn * 64 + u;
#pragma unroll
      for (int j = 0; j < 4; ++j) {
        float v = acc[i][j][r] + bcol[j];
        v = v >= 0.f ? v : slope * v;
        C[ro + j * 16] = f2b(v);
      }
    }
}

// ---------------------------------------------------------------------------
// Fused F1/F2/complex-product kernel (r8, verified).
// Each block computes BOTH K=128 GEMM passes for its (m,n) tile, then writes
// F1 <- acc1 (.)complex acc2 once, from f32 registers.
// Cross-pass LDS WAR race-free (see r8 proof). vmcnt ladder 12/8/4/0.
// ---------------------------------------------------------------------------
__device__ __forceinline__ void f_pass(
    const u16* gA0, const u16* gA1, const u16* gB0, const u16* gB1,
    short (*Asb)[128 * 32], short (*Bsb)[128 * 32],
    int lo0, int lo1, const int* offA, const int* offB,
    v4f (&acc)[4][4])
{
  auto stage = [&](int s, int buf) {
    const int k0 = s * 32;
    g2l16(gA0 + k0, &Asb[buf][lo0]);
    g2l16(gA1 + k0, &Asb[buf][lo1]);
    g2l16(gB0 + k0, &Bsb[buf][lo0]);
    g2l16(gB1 + k0, &Bsb[buf][lo1]);
  };
  stage(0, 0); stage(1, 1); stage(2, 2);
#pragma unroll
  for (int t = 0; t < 4; ++t) {
    if (t == 0) stage(3, 3);
    if (t == 0)      asm volatile("s_waitcnt vmcnt(12)" ::: "memory");
    else if (t == 1) asm volatile("s_waitcnt vmcnt(8)"  ::: "memory");
    else if (t == 2) asm volatile("s_waitcnt vmcnt(4)"  ::: "memory");
    else             asm volatile("s_waitcnt vmcnt(0)"  ::: "memory");
    __builtin_amdgcn_s_barrier();
    asm volatile("" ::: "memory");
    v8s a[4], b[4];
#pragma unroll
    for (int i = 0; i < 4; ++i) a[i] = *(const v8s*)&Asb[t][offA[i]];
#pragma unroll
    for (int j = 0; j < 4; ++j) b[j] = *(const v8s*)&Bsb[t][offB[j]];
    __builtin_amdgcn_s_setprio(1);
#pragma unroll
    for (int i = 0; i < 4; ++i)
#pragma unroll
      for (int j = 0; j < 4; ++j)
        acc[i][j] = __builtin_amdgcn_mfma_f32_16x16x32_bf16(a[i], b[j], acc[i][j], 0, 0, 0);
    __builtin_amdgcn_s_setprio(0);
  }
}

__global__ __launch_bounds__(256) void gemm_f1f2(
    const u16* __restrict__ E3,    // [2*BATCH][128]; rows B.. = centers
    const u16* __restrict__ C1t,   // [NF][128]
    const u16* __restrict__ C2t,   // [NF][128]
    u16* __restrict__ F1)          // [BATCH][NF] <- F1 .* F2
{
  __shared__ __align__(16) short Asb[5][128 * 32];
  __shared__ __align__(16) short Bsb[5][128 * 32];

  const int tid  = threadIdx.x;
  const int wave = tid >> 6, lane = tid & 63;
  const int wm = wave >> 1, wn = wave & 1;
  const int u = lane & 15, quad = lane >> 4;
  const int N = NF, K = H3_DIM;

  const int nwg = gridDim.x * gridDim.y;
  int id = blockIdx.y * gridDim.x + blockIdx.x;
  if ((nwg & 7) == 0) id = (id & 7) * (nwg >> 3) + (id >> 3);
  const int m0 = (id / gridDim.x) * 128, n0 = (id % gridDim.x) * 128;

  const int g_log = ((lane & 3) - ((lane >> 3) & 3)) & 3;
  const int srow  = wave * 32 + (lane >> 2);
  const size_t aoffX = (size_t)(m0 + srow) * K + g_log * 8;
  const size_t boff  = (size_t)(n0 + srow) * K + g_log * 8;
  const int lo0 = (wave * 32)      * 32;
  const int lo1 = (wave * 32 + 16) * 32;

  const int gran = (quad + (u >> 1)) & 3;
  int offA[4], offB[4];
#pragma unroll
  for (int i = 0; i < 4; ++i) {
    offA[i] = (wm * 64 + i * 16 + u) * 32 + gran * 8;
    offB[i] = (wn * 64 + i * 16 + u) * 32 + gran * 8;
  }

  v4f acc1[4][4], acc2[4][4];
#pragma unroll
  for (int i = 0; i < 4; ++i)
#pragma unroll
    for (int j = 0; j < 4; ++j) {
      acc1[i][j] = (v4f){0.f, 0.f, 0.f, 0.f};
      acc2[i][j] = (v4f){0.f, 0.f, 0.f, 0.f};
    }

  // pass 1: F1 = E3x @ C1^T
  f_pass(E3 + aoffX, E3 + aoffX + (size_t)16 * K,
         C1t + boff, C1t + boff + (size_t)16 * K,
         Asb, Bsb, lo0, lo1, offA, offB, acc1);
  // pass 2: F2 = E3c @ C2^T  (centers rows start at BATCH)
  const size_t aoffC = aoffX + (size_t)BATCH * K;
  f_pass(E3 + aoffC, E3 + aoffC + (size_t)16 * K,
         C2t + boff, C2t + boff + (size_t)16 * K,
         Asb, Bsb, lo0, lo1, offA, offB, acc2);

  // epilogue: complex product, all in registers.
  const bool im = (u & 1);
#pragma unroll
  for (int i = 0; i < 4; ++i)
#pragma unroll
    for (int r = 0; r < 4; ++r) {
      const size_t ro = (size_t)(m0 + wm * 64 + i * 16 + quad * 4 + r) * N
                        + n0 + wn * 64 + u;
#pragma unroll
      for (int j = 0; j < 4; ++j) {
        const float f1v = acc1[i][j][r];
        const float f1p = __shfl_xor(f1v, 1, 64);
        const float f2v = acc2[i][j][r];
        const float f2p = __shfl_xor(f2v, 1, 64);
        const float outv = im ? (f1p * f2v + f1v * f2p)
                              : (f1v * f2v - f1p * f2p);
        F1[ro + j * 16] = f2b(outv);
      }
    }
}

// ---------------------------------------------------------------------------
// prep_all (r9, verified): ONE launch for cast + transposes + C/T gen +
// zbias. Twiddles inline (bit-identical to table path).
// ---------------------------------------------------------------------------
#define CAST_NB   (BATCH * D_IN / 4 / 256)        // 16384 blocks per source
#define NB_CAST   (2 * CAST_NB)                   // 32768
#define NB_TW1    ((D_IN / 32) * (H1_DIM / 32))   // 512
#define NB_TW2    ((H1_DIM / 32) * (H2_DIM / 32)) // 128
#define NB_TW3    ((H2_DIM / 32) * (H3_DIM / 32)) // 32
#define NB_TWC1   ((D_CBP / 32) * (H_C / 32))     // 2048
#define NB_TRANS  (NB_TW1 + NB_TW2 + NB_TW3 + NB_TWC1)  // 2720
#define NB_GENC   (NF * H3_DIM / 256)             // 1088
#define NB_GENT   (NF)                            // 2176
#define NB_ZB     9
#define NB_PREP   (NB_CAST + NB_TRANS + NB_GENC + NB_GENT + NB_ZB)

__global__ __launch_bounds__(256) void prep_all(
    const float* __restrict__ X, const float* __restrict__ Centers,
    u16* __restrict__ Xb,
    const float* __restrict__ W1, u16* __restrict__ W1t,
    const float* __restrict__ W2, u16* __restrict__ W2t,
    const float* __restrict__ W3, u16* __restrict__ W3t,
    const float* __restrict__ Wc1, u16* __restrict__ Wc1t,
    const int* __restrict__ h1, const float* __restrict__ s1,
    const int* __restrict__ h2, const float* __restrict__ s2,
    u16* __restrict__ C1t, u16* __restrict__ C2t,
    u16* __restrict__ Tt, float* __restrict__ zbias)
{
  __shared__ float tile[32][33];
  int bx = blockIdx.x;
  const int t = threadIdx.x;

  if (bx < NB_CAST) {                       // ---- cast role ----
    const float* s = (bx < CAST_NB) ? X : Centers;
    const int i = ((bx < CAST_NB) ? bx : bx - CAST_NB) * 256 + t;
    u16* d = Xb + ((bx < CAST_NB) ? 0 : (size_t)BATCH * D_IN);
    const float4 v = ((const float4*)s)[i];
    __align__(8) u16 o[4] = {f2b(v.x), f2b(v.y), f2b(v.z), f2b(v.w)};
    *(uint2*)(d + (size_t)i * 4) = *(uint2*)o;
    return;
  }
  bx -= NB_CAST;

  if (bx < NB_TRANS) {                      // ---- transpose role ----
    const float* W; u16* Wt; int K, N;
    if (bx < NB_TW1)        { W = W1;  Wt = W1t;  K = D_IN;   N = H1_DIM; }
    else if (bx < NB_TW1 + NB_TW2) {
      bx -= NB_TW1;           W = W2;  Wt = W2t;  K = H1_DIM; N = H2_DIM; }
    else if (bx < NB_TW1 + NB_TW2 + NB_TW3) {
      bx -= NB_TW1 + NB_TW2;  W = W3;  Wt = W3t;  K = H2_DIM; N = H3_DIM; }
    else {
      bx -= NB_TW1 + NB_TW2 + NB_TW3;
                              W = Wc1; Wt = Wc1t; K = D_CBP;  N = H_C;    }
    const int nt = N / 32;
    const int k0 = (bx / nt) * 32, n0 = (bx % nt) * 32;
    const int tx = t & 31, ty = t >> 5;
#pragma unroll
    for (int s = 0; s < 4; ++s) {
      const int k = ty * 4 + s;
      tile[k][tx] = W[(size_t)(k0 + k) * N + n0 + tx];
    }
    __syncthreads();
#pragma unroll
    for (int s = 0; s < 4; ++s) {
      const int n = ty * 4 + s;
      Wt[(size_t)(n0 + n) * K + k0 + tx] = f2b(tile[tx][n]);
    }
    return;
  }
  bx -= NB_TRANS;

  if (bx < NB_GENC) {                       // ---- gen_C role ----
    const int id = bx * 256 + t;            // [0, NF*128)
    const int m = id >> 7, i = id & 127;
    const int k = m >> 1;
    float v1 = 0.f, v2 = 0.f;
    if (m < 2 * (D_CBP / 2 + 1)) {          // m < 2050
      const float2 c1 = twiddle((k * h1[i]) & (D_CBP - 1));
      const float2 c2 = twiddle((k * h2[i]) & (D_CBP - 1));
      v1 = (m & 1) ? -s1[i] * c1.y : s1[i] * c1.x;
      v2 = (m & 1) ? -s2[i] * c2.y : s2[i] * c2.x;
    }
    C1t[id] = f2b(v1);
    C2t[id] = f2b(v2);
    return;
  }
  bx -= NB_GENC;

  if (bx < NB_GENT) {                       // ---- gen_T role ----
    const int id = bx * 256 + t;            // [0, NF*256)
    const int m = id >> 8, q0 = (id & 255) * 8;
    const int k = m >> 1;
    const float sc = ((k == 0) || (k == D_CBP / 2)) ? (1.f / D_CBP)
                                                    : (2.f / D_CBP);
    __align__(16) u16 o[8];
#pragma unroll
    for (int j = 0; j < 8; ++j) {
      float v = 0.f;
      if (m < 2 * (D_CBP / 2 + 1)) {
        const float2 cs = twiddle((k * (q0 + j)) & (D_CBP - 1));
        v = (m & 1) ? -sc * cs.y : sc * cs.x;
      }
      o[j] = f2b(v);
    }
    *(v8s*)&Tt[(size_t)m * D_CBP + q0] = *(v8s*)o;
    return;
  }
  bx -= NB_GENT;

  {                                         // ---- zbias role ----
    const int i = bx * 256 + t;
    if (i < NF) zbias[i] = 0.f;
  }
}

// ---------------------------------------------------------------------------
// Head: logits = Z[B,1024](bf16) @ Wc2[1024,10] + bc2; softmax -> fp32 out.
// ---------------------------------------------------------------------------
__global__ __launch_bounds__(256) void head_softmax(
    const u16* __restrict__ Z, const float* __restrict__ Wc2,
    const float* __restrict__ bc2, float* __restrict__ out)
{
  const int row  = blockIdx.x * 4 + (threadIdx.x >> 6);
  const int lane = threadIdx.x & 63;

  float acc[CLASSES];
#pragma unroll
  for (int c = 0; c < CLASSES; ++c) acc[c] = 0.f;

  const u16* z = Z + (size_t)row * H_C;
  for (int k = lane; k < H_C; k += 64) {
    const float zv = b2f(z[k]);
    const float* w = Wc2 + (size_t)k * CLASSES;
#pragma unroll
    for (int c = 0; c < CLASSES; ++c) acc[c] += zv * w[c];
  }
#pragma unroll
  for (int c = 0; c < CLASSES; ++c) {
#pragma unroll
    for (int off = 32; off > 0; off >>= 1)
      acc[c] += __shfl_down(acc[c], off);
  }
  if (lane == 0) {
    float l[CLASSES], mx = -1e30f;
#pragma unroll
    for (int c = 0; c < CLASSES; ++c) { l[c] = acc[c] + bc2[c]; mx = fmaxf(mx, l[c]); }
    float s = 0.f;
#pragma unroll
    for (int c = 0; c < CLASSES; ++c) { l[c] = __expf(l[c] - mx); s += l[c]; }
    const float inv = 1.f / s;
#pragma unroll
    for (int c = 0; c < CLASSES; ++c) out[(size_t)row * CLASSES + c] = l[c] * inv;
  }
}

// ---------------------------------------------------------------------------
// Launcher (8 dispatches).  Workspace map as r9 (peak < 128 MiB).
// G1 / G4' on the pipelined 256^2 engine; G2/G3/FWt on the 128^2 engine.
// ---------------------------------------------------------------------------
extern "C" void kernel_launch(void* const* d_in, const int* in_sizes, int n_in,
                              void* d_out, int out_size, void* d_ws, size_t ws_size,
                              hipStream_t stream) {
  const float* X       = (const float*)d_in[0];
  const float* Centers = (const float*)d_in[1];
  const float* W1      = (const float*)d_in[2];
  const float* b1      = (const float*)d_in[3];
  const float* W2      = (const float*)d_in[4];
  const float* b2      = (const float*)d_in[5];
  const float* W3      = (const float*)d_in[6];
  const float* b3      = (const float*)d_in[7];
  const int*   h1      = (const int*)d_in[8];
  const float* s1      = (const float*)d_in[9];
  const int*   h2      = (const int*)d_in[10];
  const float* s2      = (const float*)d_in[11];
  const float* Wc1     = (const float*)d_in[12];
  const float* bc1     = (const float*)d_in[13];
  const float* Wc2     = (const float*)d_in[14];
  const float* bc2     = (const float*)d_in[15];
  float* out = (float*)d_out;

  char* ws = (char*)d_ws;
  const size_t MB = 1u << 20;
  const size_t KB = 1u << 10;
  u16*    Xb    = (u16*)(ws);
  u16*    FWt   = (u16*)(ws + 8 * MB + 512 * KB);
  u16*    F1    = (u16*)(ws + 13 * MB);
  u16*    E1b   = (u16*)(ws + 64 * MB);
  u16*    Zb    = (u16*)(ws + 81 * MB);
  u16*    E2b   = (u16*)(ws + 96 * MB);
  u16*    Tt    = (u16*)(ws + 96 * MB);             // dead before G2
  u16*    E3b   = (u16*)(ws + 113 * MB);
  u16*    W1t   = (u16*)(ws + 121 * MB);
  u16*    W2t   = (u16*)(ws + 122 * MB);
  u16*    W3t   = (u16*)(ws + 122 * MB + 256 * KB);
  u16*    Wc1t  = (u16*)(ws + 122 * MB + 512 * KB);
  u16*    C1t   = (u16*)(ws + 126 * MB + 512 * KB);
  u16*    C2t   = (u16*)(ws + 127 * MB + 64 * KB);
  float*  zbias = (float*)(ws + 127 * MB + 672 * KB);

  const dim3 blk(256), blk512(512);

  // all input prep in one launch
  prep_all<<<dim3(NB_PREP), blk, 0, stream>>>(
      X, Centers, Xb, W1, W1t, W2, W2t, W3, W3t, Wc1, Wc1t,
      h1, s1, h2, s2, C1t, C2t, Tt, zbias);

  // G1 on the 256^2 engine (grid 2x128 = 256 blocks, 1/CU)
  gemm256_bf16<<<dim3(H1_DIM / 256, 2 * BATCH / 256), blk512, 0, stream>>>(
      Xb, W1t, b1, E1b, 2 * BATCH, H1_DIM, D_IN, D_IN, D_IN, SLOPE);

  // FWt = Wc1t @ Tt^T   [1024][2176]   (consumes Tt before G2 kills it)
  gemm_bf16<<<dim3(NF / 128, H_C / 128), blk, 0, stream>>>(
      Wc1t, Tt, zbias, FWt, H_C, NF, D_CBP, D_CBP, D_CBP, 1.0f);

  // G2, G3 on the 128^2 engine
  gemm_bf16<<<dim3(H2_DIM / 128, 2 * BATCH / 128), blk, 0, stream>>>(
      E1b, W2t, b2, E2b, 2 * BATCH, H2_DIM, H1_DIM, H1_DIM, H1_DIM, SLOPE);
  gemm_bf16<<<dim3(H3_DIM / 128, 2 * BATCH / 128), blk, 0, stream>>>(
      E2b, W3t, b3, E3b, 2 * BATCH, H3_DIM, H2_DIM, H2_DIM, H2_DIM, SLOPE);

  // P = F1 .* F2, fused dual-GEMM, register complex product
  gemm_f1f2<<<dim3(NF / 128, BATCH / 128), blk, 0, stream>>>(
      E3b, C1t, C2t, F1);

  // Z = lrelu(P @ FWt^T + bc1) on the 256^2 engine (grid 4x64 = 256 blocks)
  gemm256_bf16<<<dim3(H_C / 256, BATCH / 256), blk512, 0, stream>>>(
      F1, FWt, bc1, Zb, BATCH, H_C, NF_USED, NF, NF, SLOPE);

  // head
  head_softmax<<<dim3(BATCH / 4), blk, 0, stream>>>(Zb, Wc2, bc2, out);
}

// Round 14
// 423.892 us; speedup vs baseline: 4.0593x; 4.0593x over previous
//
#include <hip/hip_runtime.h>
#include <hip/hip_bf16.h>
#include <math.h>

// ---------------------------------------------------------------------------
// Dims (fixed per reference)
// ---------------------------------------------------------------------------
#define BATCH   16384
#define D_IN    1024
#define H1_DIM  512
#define H2_DIM  256
#define H3_DIM  128
#define D_CBP   2048
#define H_C     1024
#define CLASSES 10
#define SLOPE   0.2f

// FFT-domain dims: rfft bins k = 0..1024 (1025), padded to 1088 complex
// -> 2176 real columns (Re,Im interleaved), = 17 tiles of 128.
// Non-zero real columns: 2*1025 = 2050 -> K-trim to 2080 (mult of 32).
#define NK_PAD  1088
#define NF      (2 * NK_PAD)   // 2176
#define NF_USED 2080           // K-trim for G4' (cols 2050.. are zeros)

typedef short v8s __attribute__((ext_vector_type(8)));
typedef float v4f __attribute__((ext_vector_type(4)));
typedef unsigned short u16;
typedef unsigned int   u32;

__device__ __forceinline__ float b2f(unsigned short u) {
  return __uint_as_float(((unsigned)u) << 16);
}
__device__ __forceinline__ u16 f2b(float f) {
  __hip_bfloat16 h = __float2bfloat16(f);   // RNE
  return __builtin_bit_cast(unsigned short, h);
}

// twiddle (cos,sin)(2π idx/2048) — same expression the old table used,
// so values are bit-identical to the r8 tab[] path.
__device__ __forceinline__ float2 twiddle(int idx) {
  const float ang = 6.2831853071795864769f * (float)idx / 2048.f;
  return make_float2(__cosf(ang), __sinf(ang));
}

// async 16B global->LDS (direct-to-shared DMA). LDS dest = wave-uniform base
// + lane*16 -> LDS layout is forced packed lane-order.
__device__ __forceinline__ void g2l16(const void* g, void* l) {
  __builtin_amdgcn_global_load_lds(
      (const __attribute__((address_space(1))) void*)g,
      (__attribute__((address_space(3))) void*)l, 16, 0, 0);
}

// ---------------------------------------------------------------------------
// 128^2 bf16 MFMA GEMM (verified r6-r9 engine): 4 waves, BK=32, 5-buffer
// ring, prefetch depth 3, one barrier/step, counted vmcnt (12/8/4/0).
// Granule rotation swizzle at the GLOBAL address -> conflict-free ds_read.
// Bijective XCD swizzle. Used for G2/G3/FWt (small/odd-N GEMMs).
// ---------------------------------------------------------------------------
__global__ __launch_bounds__(256) void gemm_bf16(
    const u16* __restrict__ A,   // [M][lda] bf16
    const u16* __restrict__ Bt,  // [N][ldb] bf16  (weights pre-transposed)
    const float* __restrict__ bias,
    u16* __restrict__ C,         // [M][N] bf16
    int M, int N, int K, int lda, int ldb, float slope)
{
  __shared__ __align__(16) short Asb[5][128 * 32];   // 40 KiB
  __shared__ __align__(16) short Bsb[5][128 * 32];   // 40 KiB

  const int tid  = threadIdx.x;
  const int wave = tid >> 6, lane = tid & 63;
  const int wm = wave >> 1, wn = wave & 1;
  const int u = lane & 15, quad = lane >> 4;

  const int nwg = gridDim.x * gridDim.y;
  int id = blockIdx.y * gridDim.x + blockIdx.x;
  if ((nwg & 7) == 0) id = (id & 7) * (nwg >> 3) + (id >> 3);
  const int m0 = (id / gridDim.x) * 128, n0 = (id % gridDim.x) * 128;

  const int g_log = ((lane & 3) - ((lane >> 3) & 3)) & 3;
  const int srow  = wave * 32 + (lane >> 2);
  const u16* gA0 = A  + (size_t)(m0 + srow)      * lda + g_log * 8;
  const u16* gA1 = A  + (size_t)(m0 + srow + 16) * lda + g_log * 8;
  const u16* gB0 = Bt + (size_t)(n0 + srow)      * ldb + g_log * 8;
  const u16* gB1 = Bt + (size_t)(n0 + srow + 16) * ldb + g_log * 8;
  const int lo0 = (wave * 32)      * 32;
  const int lo1 = (wave * 32 + 16) * 32;

  const int gran = (quad + (u >> 1)) & 3;
  int offA[4], offB[4];
#pragma unroll
  for (int i = 0; i < 4; ++i) {
    offA[i] = (wm * 64 + i * 16 + u) * 32 + gran * 8;
    offB[i] = (wn * 64 + i * 16 + u) * 32 + gran * 8;
  }

  v4f acc[4][4];
#pragma unroll
  for (int i = 0; i < 4; ++i)
#pragma unroll
    for (int j = 0; j < 4; ++j) acc[i][j] = (v4f){0.f, 0.f, 0.f, 0.f};

  const int nsteps = K >> 5;   // BK=32

  auto stage = [&](int s, int buf) {
    const int k0 = s * 32;
    g2l16(gA0 + k0, &Asb[buf][lo0]);
    g2l16(gA1 + k0, &Asb[buf][lo1]);
    g2l16(gB0 + k0, &Bsb[buf][lo0]);
    g2l16(gB1 + k0, &Bsb[buf][lo1]);
  };

  stage(0, 0);
  if (nsteps > 1) stage(1, 1);
  if (nsteps > 2) stage(2, 2);

  int cb = 0, sb = 3;   // compute-buffer, stage-buffer (wrap mod 5)
  for (int t = 0; t < nsteps; ++t) {
    if (t + 3 < nsteps) stage(t + 3, sb);

    const int rem = nsteps - 1 - t;
    if (rem >= 3)      asm volatile("s_waitcnt vmcnt(12)" ::: "memory");
    else if (rem == 2) asm volatile("s_waitcnt vmcnt(8)"  ::: "memory");
    else if (rem == 1) asm volatile("s_waitcnt vmcnt(4)"  ::: "memory");
    else               asm volatile("s_waitcnt vmcnt(0)"  ::: "memory");
    __builtin_amdgcn_s_barrier();
    asm volatile("" ::: "memory");   // pin ds_reads below the barrier

    v8s a[4], b[4];
#pragma unroll
    for (int i = 0; i < 4; ++i) a[i] = *(const v8s*)&Asb[cb][offA[i]];
#pragma unroll
    for (int j = 0; j < 4; ++j) b[j] = *(const v8s*)&Bsb[cb][offB[j]];
    __builtin_amdgcn_s_setprio(1);
#pragma unroll
    for (int i = 0; i < 4; ++i)
#pragma unroll
      for (int j = 0; j < 4; ++j)
        acc[i][j] = __builtin_amdgcn_mfma_f32_16x16x32_bf16(a[i], b[j], acc[i][j], 0, 0, 0);
    __builtin_amdgcn_s_setprio(0);

    cb = (cb == 4) ? 0 : cb + 1;
    sb = (sb == 4) ? 0 : sb + 1;
  }

  // C/D layout (m89-verified): col = lane&15, row = quad*4 + reg
  float bcol[4];
#pragma unroll
  for (int j = 0; j < 4; ++j) bcol[j] = bias[n0 + wn * 64 + j * 16 + u];
#pragma unroll
  for (int i = 0; i < 4; ++i)
#pragma unroll
    for (int r = 0; r < 4; ++r) {
      const size_t ro = (size_t)(m0 + wm * 64 + i * 16 + quad * 4 + r) * N
                        + n0 + wn * 64 + u;
#pragma unroll
      for (int j = 0; j < 4; ++j) {
        float v = acc[i][j][r] + bcol[j];
        v = v >= 0.f ? v : slope * v;
        C[ro + j * 16] = f2b(v);
      }
    }
}

// ---------------------------------------------------------------------------
// 256^2 bf16 MFMA GEMM — r10 body (verified 73.3 µs on G4', VGPR 100).
// 8 waves (2M x 4N), BK=32, ring-4 LDS, prefetch depth 2, one barrier/step,
// counted vmcnt 8/4/0, ds_reads after the barrier feeding MFMA directly.
// [r12/r13 lesson: zero-copy dual register sets (~240 regs) spill at 512
//  threads — hipcc caps at 128 VGPR/wave regardless of launch_bounds hint.
//  Register pipelining at this width only works with the copy-rotate form
//  (gemm256p below), which fits in 124.]
// Requires M%256==0 && N%256==0. Used for G4' (K=2080: copy tax loses).
// ---------------------------------------------------------------------------
__global__ __launch_bounds__(512) void gemm256_bf16(
    const u16* __restrict__ A,   // [M][lda] bf16
    const u16* __restrict__ Bt,  // [N][ldb] bf16
    const float* __restrict__ bias,
    u16* __restrict__ C,         // [M][N] bf16
    int M, int N, int K, int lda, int ldb, float slope)
{
  __shared__ __align__(16) short Asb[4][256 * 32];   // 64 KiB
  __shared__ __align__(16) short Bsb[4][256 * 32];   // 64 KiB

  const int tid  = threadIdx.x;
  const int wave = tid >> 6, lane = tid & 63;
  const int wm = wave >> 2, wn = wave & 3;     // 2 x 4 wave grid
  const int u = lane & 15, quad = lane >> 4;

  const int nwg = gridDim.x * gridDim.y;
  int id = blockIdx.y * gridDim.x + blockIdx.x;
  if ((nwg & 7) == 0) id = (id & 7) * (nwg >> 3) + (id >> 3);
  const int m0 = (id / gridDim.x) * 256, n0 = (id % gridDim.x) * 256;

  const int g_log = ((lane & 3) - ((lane >> 3) & 3)) & 3;
  const int srow  = wave * 32 + (lane >> 2);   // 8 waves -> rows 0..255
  const u16* gA0 = A  + (size_t)(m0 + srow)      * lda + g_log * 8;
  const u16* gA1 = A  + (size_t)(m0 + srow + 16) * lda + g_log * 8;
  const u16* gB0 = Bt + (size_t)(n0 + srow)      * ldb + g_log * 8;
  const u16* gB1 = Bt + (size_t)(n0 + srow + 16) * ldb + g_log * 8;
  const int lo0 = (wave * 32)      * 32;
  const int lo1 = (wave * 32 + 16) * 32;

  const int gran = (quad + (u >> 1)) & 3;
  int offA[8], offB[4];
#pragma unroll
  for (int i = 0; i < 8; ++i)
    offA[i] = (wm * 128 + i * 16 + u) * 32 + gran * 8;
#pragma unroll
  for (int j = 0; j < 4; ++j)
    offB[j] = (wn * 64 + j * 16 + u) * 32 + gran * 8;

  v4f acc[8][4];
#pragma unroll
  for (int i = 0; i < 8; ++i)
#pragma unroll
    for (int j = 0; j < 4; ++j) acc[i][j] = (v4f){0.f, 0.f, 0.f, 0.f};

  const int nsteps = K >> 5;   // BK=32

  auto stage = [&](int s) {
    const int k0 = s * 32, buf = s & 3;
    g2l16(gA0 + k0, &Asb[buf][lo0]);
    g2l16(gA1 + k0, &Asb[buf][lo1]);
    g2l16(gB0 + k0, &Bsb[buf][lo0]);
    g2l16(gB1 + k0, &Bsb[buf][lo1]);
  };

  stage(0);
  if (nsteps > 1) stage(1);

  for (int t = 0; t < nsteps; ++t) {
    if (t + 2 < nsteps) stage(t + 2);

    const int rem = nsteps - 1 - t;
    if (rem >= 2)      asm volatile("s_waitcnt vmcnt(8)" ::: "memory");
    else if (rem == 1) asm volatile("s_waitcnt vmcnt(4)" ::: "memory");
    else               asm volatile("s_waitcnt vmcnt(0)" ::: "memory");
    __builtin_amdgcn_s_barrier();
    asm volatile("" ::: "memory");   // pin ds_reads below the barrier

    const int cb = t & 3;
    v8s a[8], b[4];
#pragma unroll
    for (int i = 0; i < 8; ++i) a[i] = *(const v8s*)&Asb[cb][offA[i]];
#pragma unroll
    for (int j = 0; j < 4; ++j) b[j] = *(const v8s*)&Bsb[cb][offB[j]];
    __builtin_amdgcn_s_setprio(1);
#pragma unroll
    for (int i = 0; i < 8; ++i)
#pragma unroll
      for (int j = 0; j < 4; ++j)
        acc[i][j] = __builtin_amdgcn_mfma_f32_16x16x32_bf16(a[i], b[j], acc[i][j], 0, 0, 0);
    __builtin_amdgcn_s_setprio(0);
  }

  // C/D layout: col = lane&15, row = quad*4 + reg
  float bcol[4];
#pragma unroll
  for (int j = 0; j < 4; ++j) bcol[j] = bias[n0 + wn * 64 + j * 16 + u];
#pragma unroll
  for (int i = 0; i < 8; ++i)
#pragma unroll
    for (int r = 0; r < 4; ++r) {
      const size_t ro = (size_t)(m0 + wm * 128 + i * 16 + quad * 4 + r) * N
                        + n0 + wn * 64 + u;
#pragma unroll
      for (int j = 0; j < 4; ++j) {
        float v = acc[i][j][r] + bcol[j];
        v = v >= 0.f ? v : slope * v;
        C[ro + j * 16] = f2b(v);
      }
    }
}

// ---------------------------------------------------------------------------
// 256^2 engine, copy-rotate register pipeline — r11 body (verified: G1 ~20
// µs, VGPR 124, no spill). ds_reads for step t+1 issued after the barrier
// into a_n/b_n, complete under MFMA(t); copy-rotate tail (48 v_mov/step) is
// the price — wins at small nsteps (G1, K=1024), loses at K=2080 (G4').
// ---------------------------------------------------------------------------
__global__ __launch_bounds__(512) void gemm256p_bf16(
    const u16* __restrict__ A,   // [M][lda] bf16
    const u16* __restrict__ Bt,  // [N][ldb] bf16
    const float* __restrict__ bias,
    u16* __restrict__ C,         // [M][N] bf16
    int M, int N, int K, int lda, int ldb, float slope)
{
  __shared__ __align__(16) short Asb[4][256 * 32];   // 64 KiB
  __shared__ __align__(16) short Bsb[4][256 * 32];   // 64 KiB

  const int tid  = threadIdx.x;
  const int wave = tid >> 6, lane = tid & 63;
  const int wm = wave >> 2, wn = wave & 3;     // 2 x 4 wave grid
  const int u = lane & 15, quad = lane >> 4;

  const int nwg = gridDim.x * gridDim.y;
  int id = blockIdx.y * gridDim.x + blockIdx.x;
  if ((nwg & 7) == 0) id = (id & 7) * (nwg >> 3) + (id >> 3);
  const int m0 = (id / gridDim.x) * 256, n0 = (id % gridDim.x) * 256;

  const int g_log = ((lane & 3) - ((lane >> 3) & 3)) & 3;
  const int srow  = wave * 32 + (lane >> 2);   // 8 waves -> rows 0..255
  const u16* gA0 = A  + (size_t)(m0 + srow)      * lda + g_log * 8;
  const u16* gA1 = A  + (size_t)(m0 + srow + 16) * lda + g_log * 8;
  const u16* gB0 = Bt + (size_t)(n0 + srow)      * ldb + g_log * 8;
  const u16* gB1 = Bt + (size_t)(n0 + srow + 16) * ldb + g_log * 8;
  const int lo0 = (wave * 32)      * 32;
  const int lo1 = (wave * 32 + 16) * 32;

  const int gran = (quad + (u >> 1)) & 3;
  int offA[8], offB[4];
#pragma unroll
  for (int i = 0; i < 8; ++i)
    offA[i] = (wm * 128 + i * 16 + u) * 32 + gran * 8;
#pragma unroll
  for (int j = 0; j < 4; ++j)
    offB[j] = (wn * 64 + j * 16 + u) * 32 + gran * 8;

  v4f acc[8][4];
#pragma unroll
  for (int i = 0; i < 8; ++i)
#pragma unroll
    for (int j = 0; j < 4; ++j) acc[i][j] = (v4f){0.f, 0.f, 0.f, 0.f};

  const int nsteps = K >> 5;   // BK=32

  auto stage = [&](int s) {
    const int k0 = s * 32, buf = s & 3;
    g2l16(gA0 + k0, &Asb[buf][lo0]);
    g2l16(gA1 + k0, &Asb[buf][lo1]);
    g2l16(gB0 + k0, &Bsb[buf][lo0]);
    g2l16(gB1 + k0, &Bsb[buf][lo1]);
  };

  // prologue: stage 0..2, wait step 0, pre-issue reads of buf0
  stage(0);
  if (nsteps > 1) stage(1);
  if (nsteps > 2) stage(2);
  if (nsteps > 2)      asm volatile("s_waitcnt vmcnt(8)" ::: "memory");
  else if (nsteps > 1) asm volatile("s_waitcnt vmcnt(4)" ::: "memory");
  else                 asm volatile("s_waitcnt vmcnt(0)" ::: "memory");
  __builtin_amdgcn_s_barrier();
  asm volatile("" ::: "memory");

  v8s a_c[8], b_c[4], a_n[8], b_n[4];
#pragma unroll
  for (int i = 0; i < 8; ++i) a_c[i] = *(const v8s*)&Asb[0][offA[i]];
#pragma unroll
  for (int j = 0; j < 4; ++j) b_c[j] = *(const v8s*)&Bsb[0][offB[j]];

  for (int t = 0; t < nsteps; ++t) {
    const int rem = nsteps - 1 - t;
    if (rem > 0) {
      if (rem >= 2) asm volatile("s_waitcnt vmcnt(4)" ::: "memory");
      else          asm volatile("s_waitcnt vmcnt(0)" ::: "memory");
      __builtin_amdgcn_s_barrier();
      asm volatile("" ::: "memory");   // pin ds_reads below the barrier
      const int nb = (t + 1) & 3;
#pragma unroll
      for (int i = 0; i < 8; ++i) a_n[i] = *(const v8s*)&Asb[nb][offA[i]];
#pragma unroll
      for (int j = 0; j < 4; ++j) b_n[j] = *(const v8s*)&Bsb[nb][offB[j]];
    }

    __builtin_amdgcn_s_setprio(1);
#pragma unroll
    for (int i = 0; i < 8; ++i)
#pragma unroll
      for (int j = 0; j < 4; ++j)
        acc[i][j] = __builtin_amdgcn_mfma_f32_16x16x32_bf16(a_c[i], b_c[j], acc[i][j], 0, 0, 0);
    __builtin_amdgcn_s_setprio(0);

    if (t + 3 < nsteps) stage(t + 3);   // overwrites buf (t-1)&3: safe

    if (rem > 0) {
#pragma unroll
      for (int i = 0; i < 8; ++i) a_c[i] = a_n[i];
#pragma unroll
      for (int j = 0; j < 4; ++j) b_c[j] = b_n[j];
    }
  }

  // C/D layout: col = lane&15, row = quad*4 + reg
  float bcol[4];
#pragma unroll
  for (int j = 0; j < 4; ++j) bcol[j] = bias[n0 + wn * 64 + j * 16 + u];
#pragma unroll
  for (int i = 0; i < 8; ++i)
#pragma unroll
    for (int r = 0; r < 4; ++r) {
      const size_t ro = (size_t)(m0 + wm * 128 + i * 16 + quad * 4 + r) * N
                        + n0 + wn * 64 + u;
#pragma unroll
      for (int j = 0; j < 4; ++j) {
        float v = acc[i][j][r] + bcol[j];
        v = v >= 0.f ? v : slope * v;
        C[ro + j * 16] = f2b(v);
      }
    }
}

// ---------------------------------------------------------------------------
// Fused F1/F2/complex-product kernel (r8, verified).
// ---------------------------------------------------------------------------
__device__ __forceinline__ void f_pass(
    const u16* gA0, const u16* gA1, const u16* gB0, const u16* gB1,
    short (*Asb)[128 * 32], short (*Bsb)[128 * 32],
    int lo0, int lo1, const int* offA, const int* offB,
    v4f (&acc)[4][4])
{
  auto stage = [&](int s, int buf) {
    const int k0 = s * 32;
    g2l16(gA0 + k0, &Asb[buf][lo0]);
    g2l16(gA1 + k0, &Asb[buf][lo1]);
    g2l16(gB0 + k0, &Bsb[buf][lo0]);
    g2l16(gB1 + k0, &Bsb[buf][lo1]);
  };
  stage(0, 0); stage(1, 1); stage(2, 2);
#pragma unroll
  for (int t = 0; t < 4; ++t) {
    if (t == 0) stage(3, 3);
    if (t == 0)      asm volatile("s_waitcnt vmcnt(12)" ::: "memory");
    else if (t == 1) asm volatile("s_waitcnt vmcnt(8)"  ::: "memory");
    else if (t == 2) asm volatile("s_waitcnt vmcnt(4)"  ::: "memory");
    else             asm volatile("s_waitcnt vmcnt(0)"  ::: "memory");
    __builtin_amdgcn_s_barrier();
    asm volatile("" ::: "memory");
    v8s a[4], b[4];
#pragma unroll
    for (int i = 0; i < 4; ++i) a[i] = *(const v8s*)&Asb[t][offA[i]];
#pragma unroll
    for (int j = 0; j < 4; ++j) b[j] = *(const v8s*)&Bsb[t][offB[j]];
    __builtin_amdgcn_s_setprio(1);
#pragma unroll
    for (int i = 0; i < 4; ++i)
#pragma unroll
      for (int j = 0; j < 4; ++j)
        acc[i][j] = __builtin_amdgcn_mfma_f32_16x16x32_bf16(a[i], b[j], acc[i][j], 0, 0, 0);
    __builtin_amdgcn_s_setprio(0);
  }
}

__global__ __launch_bounds__(256) void gemm_f1f2(
    const u16* __restrict__ E3,    // [2*BATCH][128]; rows B.. = centers
    const u16* __restrict__ C1t,   // [NF][128]
    const u16* __restrict__ C2t,   // [NF][128]
    u16* __restrict__ F1)          // [BATCH][NF] <- F1 .* F2
{
  __shared__ __align__(16) short Asb[5][128 * 32];
  __shared__ __align__(16) short Bsb[5][128 * 32];

  const int tid  = threadIdx.x;
  const int wave = tid >> 6, lane = tid & 63;
  const int wm = wave >> 1, wn = wave & 1;
  const int u = lane & 15, quad = lane >> 4;
  const int N = NF, K = H3_DIM;

  const int nwg = gridDim.x * gridDim.y;
  int id = blockIdx.y * gridDim.x + blockIdx.x;
  if ((nwg & 7) == 0) id = (id & 7) * (nwg >> 3) + (id >> 3);
  const int m0 = (id / gridDim.x) * 128, n0 = (id % gridDim.x) * 128;

  const int g_log = ((lane & 3) - ((lane >> 3) & 3)) & 3;
  const int srow  = wave * 32 + (lane >> 2);
  const size_t aoffX = (size_t)(m0 + srow) * K + g_log * 8;
  const size_t boff  = (size_t)(n0 + srow) * K + g_log * 8;
  const int lo0 = (wave * 32)      * 32;
  const int lo1 = (wave * 32 + 16) * 32;

  const int gran = (quad + (u >> 1)) & 3;
  int offA[4], offB[4];
#pragma unroll
  for (int i = 0; i < 4; ++i) {
    offA[i] = (wm * 64 + i * 16 + u) * 32 + gran * 8;
    offB[i] = (wn * 64 + i * 16 + u) * 32 + gran * 8;
  }

  v4f acc1[4][4], acc2[4][4];
#pragma unroll
  for (int i = 0; i < 4; ++i)
#pragma unroll
    for (int j = 0; j < 4; ++j) {
      acc1[i][j] = (v4f){0.f, 0.f, 0.f, 0.f};
      acc2[i][j] = (v4f){0.f, 0.f, 0.f, 0.f};
    }

  // pass 1: F1 = E3x @ C1^T
  f_pass(E3 + aoffX, E3 + aoffX + (size_t)16 * K,
         C1t + boff, C1t + boff + (size_t)16 * K,
         Asb, Bsb, lo0, lo1, offA, offB, acc1);
  // pass 2: F2 = E3c @ C2^T  (centers rows start at BATCH)
  const size_t aoffC = aoffX + (size_t)BATCH * K;
  f_pass(E3 + aoffC, E3 + aoffC + (size_t)16 * K,
         C2t + boff, C2t + boff + (size_t)16 * K,
         Asb, Bsb, lo0, lo1, offA, offB, acc2);

  // epilogue: complex product, all in registers.
  const bool im = (u & 1);
#pragma unroll
  for (int i = 0; i < 4; ++i)
#pragma unroll
    for (int r = 0; r < 4; ++r) {
      const size_t ro = (size_t)(m0 + wm * 64 + i * 16 + quad * 4 + r) * N
                        + n0 + wn * 64 + u;
#pragma unroll
      for (int j = 0; j < 4; ++j) {
        const float f1v = acc1[i][j][r];
        const float f1p = __shfl_xor(f1v, 1, 64);
        const float f2v = acc2[i][j][r];
        const float f2p = __shfl_xor(f2v, 1, 64);
        const float outv = im ? (f1p * f2v + f1v * f2p)
                              : (f1v * f2v - f1p * f2p);
        F1[ro + j * 16] = f2b(outv);
      }
    }
}

// ---------------------------------------------------------------------------
// prep_all (r9, verified): ONE launch for cast + transposes + C/T gen +
// zbias. Twiddles inline (bit-identical to table path).
// ---------------------------------------------------------------------------
#define CAST_NB   (BATCH * D_IN / 4 / 256)        // 16384 blocks per source
#define NB_CAST   (2 * CAST_NB)                   // 32768
#define NB_TW1    ((D_IN / 32) * (H1_DIM / 32))   // 512
#define NB_TW2    ((H1_DIM / 32) * (H2_DIM / 32)) // 128
#define NB_TW3    ((H2_DIM / 32) * (H3_DIM / 32)) // 32
#define NB_TWC1   ((D_CBP / 32) * (H_C / 32))     // 2048
#define NB_TRANS  (NB_TW1 + NB_TW2 + NB_TW3 + NB_TWC1)  // 2720
#define NB_GENC   (NF * H3_DIM / 256)             // 1088
#define NB_GENT   (NF)                            // 2176
#define NB_ZB     9
#define NB_PREP   (NB_CAST + NB_TRANS + NB_GENC + NB_GENT + NB_ZB)

__global__ __launch_bounds__(256) void prep_all(
    const float* __restrict__ X, const float* __restrict__ Centers,
    u16* __restrict__ Xb,
    const float* __restrict__ W1, u16* __restrict__ W1t,
    const float* __restrict__ W2, u16* __restrict__ W2t,
    const float* __restrict__ W3, u16* __restrict__ W3t,
    const float* __restrict__ Wc1, u16* __restrict__ Wc1t,
    const int* __restrict__ h1, const float* __restrict__ s1,
    const int* __restrict__ h2, const float* __restrict__ s2,
    u16* __restrict__ C1t, u16* __restrict__ C2t,
    u16* __restrict__ Tt, float* __restrict__ zbias)
{
  __shared__ float tile[32][33];
  int bx = blockIdx.x;
  const int t = threadIdx.x;

  if (bx < NB_CAST) {                       // ---- cast role ----
    const float* s = (bx < CAST_NB) ? X : Centers;
    const int i = ((bx < CAST_NB) ? bx : bx - CAST_NB) * 256 + t;
    u16* d = Xb + ((bx < CAST_NB) ? 0 : (size_t)BATCH * D_IN);
    const float4 v = ((const float4*)s)[i];
    __align__(8) u16 o[4] = {f2b(v.x), f2b(v.y), f2b(v.z), f2b(v.w)};
    *(uint2*)(d + (size_t)i * 4) = *(uint2*)o;
    return;
  }
  bx -= NB_CAST;

  if (bx < NB_TRANS) {                      // ---- transpose role ----
    const float* W; u16* Wt; int K, N;
    if (bx < NB_TW1)        { W = W1;  Wt = W1t;  K = D_IN;   N = H1_DIM; }
    else if (bx < NB_TW1 + NB_TW2) {
      bx -= NB_TW1;           W = W2;  Wt = W2t;  K = H1_DIM; N = H2_DIM; }
    else if (bx < NB_TW1 + NB_TW2 + NB_TW3) {
      bx -= NB_TW1 + NB_TW2;  W = W3;  Wt = W3t;  K = H2_DIM; N = H3_DIM; }
    else {
      bx -= NB_TW1 + NB_TW2 + NB_TW3;
                              W = Wc1; Wt = Wc1t; K = D_CBP;  N = H_C;    }
    const int nt = N / 32;
    const int k0 = (bx / nt) * 32, n0 = (bx % nt) * 32;
    const int tx = t & 31, ty = t >> 5;
#pragma unroll
    for (int s = 0; s < 4; ++s) {
      const int k = ty * 4 + s;
      tile[k][tx] = W[(size_t)(k0 + k) * N + n0 + tx];
    }
    __syncthreads();
#pragma unroll
    for (int s = 0; s < 4; ++s) {
      const int n = ty * 4 + s;
      Wt[(size_t)(n0 + n) * K + k0 + tx] = f2b(tile[tx][n]);
    }
    return;
  }
  bx -= NB_TRANS;

  if (bx < NB_GENC) {                       // ---- gen_C role ----
    const int id = bx * 256 + t;            // [0, NF*128)
    const int m = id >> 7, i = id & 127;
    const int k = m >> 1;
    float v1 = 0.f, v2 = 0.f;
    if (m < 2 * (D_CBP / 2 + 1)) {          // m < 2050
      const float2 c1 = twiddle((k * h1[i]) & (D_CBP - 1));
      const float2 c2 = twiddle((k * h2[i]) & (D_CBP - 1));
      v1 = (m & 1) ? -s1[i] * c1.y : s1[i] * c1.x;
      v2 = (m & 1) ? -s2[i] * c2.y : s2[i] * c2.x;
    }
    C1t[id] = f2b(v1);
    C2t[id] = f2b(v2);
    return;
  }
  bx -= NB_GENC;

  if (bx < NB_GENT) {                       // ---- gen_T role ----
    const int id = bx * 256 + t;            // [0, NF*256)
    const int m = id >> 8, q0 = (id & 255) * 8;
    const int k = m >> 1;
    const float sc = ((k == 0) || (k == D_CBP / 2)) ? (1.f / D_CBP)
                                                    : (2.f / D_CBP);
    __align__(16) u16 o[8];
#pragma unroll
    for (int j = 0; j < 8; ++j) {
      float v = 0.f;
      if (m < 2 * (D_CBP / 2 + 1)) {
        const float2 cs = twiddle((k * (q0 + j)) & (D_CBP - 1));
        v = (m & 1) ? -sc * cs.y : sc * cs.x;
      }
      o[j] = f2b(v);
    }
    *(v8s*)&Tt[(size_t)m * D_CBP + q0] = *(v8s*)o;
    return;
  }
  bx -= NB_GENT;

  {                                         // ---- zbias role ----
    const int i = bx * 256 + t;
    if (i < NF) zbias[i] = 0.f;
  }
}

// ---------------------------------------------------------------------------
// Head: logits = Z[B,1024](bf16) @ Wc2[1024,10] + bc2; softmax -> fp32 out.
// ---------------------------------------------------------------------------
__global__ __launch_bounds__(256) void head_softmax(
    const u16* __restrict__ Z, const float* __restrict__ Wc2,
    const float* __restrict__ bc2, float* __restrict__ out)
{
  const int row  = blockIdx.x * 4 + (threadIdx.x >> 6);
  const int lane = threadIdx.x & 63;

  float acc[CLASSES];
#pragma unroll
  for (int c = 0; c < CLASSES; ++c) acc[c] = 0.f;

  const u16* z = Z + (size_t)row * H_C;
  for (int k = lane; k < H_C; k += 64) {
    const float zv = b2f(z[k]);
    const float* w = Wc2 + (size_t)k * CLASSES;
#pragma unroll
    for (int c = 0; c < CLASSES; ++c) acc[c] += zv * w[c];
  }
#pragma unroll
  for (int c = 0; c < CLASSES; ++c) {
#pragma unroll
    for (int off = 32; off > 0; off >>= 1)
      acc[c] += __shfl_down(acc[c], off);
  }
  if (lane == 0) {
    float l[CLASSES], mx = -1e30f;
#pragma unroll
    for (int c = 0; c < CLASSES; ++c) { l[c] = acc[c] + bc2[c]; mx = fmaxf(mx, l[c]); }
    float s = 0.f;
#pragma unroll
    for (int c = 0; c < CLASSES; ++c) { l[c] = __expf(l[c] - mx); s += l[c]; }
    const float inv = 1.f / s;
#pragma unroll
    for (int c = 0; c < CLASSES; ++c) out[(size_t)row * CLASSES + c] = l[c] * inv;
  }
}

// ---------------------------------------------------------------------------
// Launcher (8 dispatches).  Workspace map as r9 (peak < 128 MiB).
// G1 -> copy-pipelined 256^2 (r11 body, best at K=1024);
// G4' -> plain 256^2 (r10 body, best at K=2080);
// G2/G3/FWt -> 128^2 engine.
// ---------------------------------------------------------------------------
extern "C" void kernel_launch(void* const* d_in, const int* in_sizes, int n_in,
                              void* d_out, int out_size, void* d_ws, size_t ws_size,
                              hipStream_t stream) {
  const float* X       = (const float*)d_in[0];
  const float* Centers = (const float*)d_in[1];
  const float* W1      = (const float*)d_in[2];
  const float* b1      = (const float*)d_in[3];
  const float* W2      = (const float*)d_in[4];
  const float* b2      = (const float*)d_in[5];
  const float* W3      = (const float*)d_in[6];
  const float* b3      = (const float*)d_in[7];
  const int*   h1      = (const int*)d_in[8];
  const float* s1      = (const float*)d_in[9];
  const int*   h2      = (const int*)d_in[10];
  const float* s2      = (const float*)d_in[11];
  const float* Wc1     = (const float*)d_in[12];
  const float* bc1     = (const float*)d_in[13];
  const float* Wc2     = (const float*)d_in[14];
  const float* bc2     = (const float*)d_in[15];
  float* out = (float*)d_out;

  char* ws = (char*)d_ws;
  const size_t MB = 1u << 20;
  const size_t KB = 1u << 10;
  u16*    Xb    = (u16*)(ws);
  u16*    FWt   = (u16*)(ws + 8 * MB + 512 * KB);
  u16*    F1    = (u16*)(ws + 13 * MB);
  u16*    E1b   = (u16*)(ws + 64 * MB);
  u16*    Zb    = (u16*)(ws + 81 * MB);
  u16*    E2b   = (u16*)(ws + 96 * MB);
  u16*    Tt    = (u16*)(ws + 96 * MB);             // dead before G2
  u16*    E3b   = (u16*)(ws + 113 * MB);
  u16*    W1t   = (u16*)(ws + 121 * MB);
  u16*    W2t   = (u16*)(ws + 122 * MB);
  u16*    W3t   = (u16*)(ws + 122 * MB + 256 * KB);
  u16*    Wc1t  = (u16*)(ws + 122 * MB + 512 * KB);
  u16*    C1t   = (u16*)(ws + 126 * MB + 512 * KB);
  u16*    C2t   = (u16*)(ws + 127 * MB + 64 * KB);
  float*  zbias = (float*)(ws + 127 * MB + 672 * KB);

  const dim3 blk(256), blk512(512);

  // all input prep in one launch
  prep_all<<<dim3(NB_PREP), blk, 0, stream>>>(
      X, Centers, Xb, W1, W1t, W2, W2t, W3, W3t, Wc1, Wc1t,
      h1, s1, h2, s2, C1t, C2t, Tt, zbias);

  // G1 on the copy-pipelined 256^2 engine (r11 body)
  gemm256p_bf16<<<dim3(H1_DIM / 256, 2 * BATCH / 256), blk512, 0, stream>>>(
      Xb, W1t, b1, E1b, 2 * BATCH, H1_DIM, D_IN, D_IN, D_IN, SLOPE);

  // FWt = Wc1t @ Tt^T   [1024][2176]   (consumes Tt before G2 kills it)
  gemm_bf16<<<dim3(NF / 128, H_C / 128), blk, 0, stream>>>(
      Wc1t, Tt, zbias, FWt, H_C, NF, D_CBP, D_CBP, D_CBP, 1.0f);

  // G2, G3 on the 128^2 engine
  gemm_bf16<<<dim3(H2_DIM / 128, 2 * BATCH / 128), blk, 0, stream>>>(
      E1b, W2t, b2, E2b, 2 * BATCH, H2_DIM, H1_DIM, H1_DIM, H1_DIM, SLOPE);
  gemm_bf16<<<dim3(H3_DIM / 128, 2 * BATCH / 128), blk, 0, stream>>>(
      E2b, W3t, b3, E3b, 2 * BATCH, H3_DIM, H2_DIM, H2_DIM, H2_DIM, SLOPE);

  // P = F1 .* F2, fused dual-GEMM, register complex product
  gemm_f1f2<<<dim3(NF / 128, BATCH / 128), blk, 0, stream>>>(
      E3b, C1t, C2t, F1);

  // Z = lrelu(P @ FWt^T + bc1) on the plain 256^2 engine (r10 body)
  gemm256_bf16<<<dim3(H_C / 256, BATCH / 256), blk512, 0, stream>>>(
      F1, FWt, bc1, Zb, BATCH, H_C, NF_USED, NF, NF, SLOPE);

  // head
  head_softmax<<<dim3(BATCH / 4), blk, 0, stream>>>(Zb, Wc2, bc2, out);
}